// Round 4
// baseline (1012.689 us; speedup 1.0000x reference)
//
#include <hip/hip_runtime.h>

#define BATCH 16
#define CIN   200
#define T1    8192
#define COUTC 400
#define TT2   4096
#define NJ    25
#define NGROUP 10
#define CPG   40
#define NPOOL 14

__constant__ int NBR_OFF[NJ + 1] = {0,8,14,18,21,29,35,39,42,50,56,63,72,80,85,94,101,106,110,113,122,129,134,138,141,145};
__constant__ int NBR[145] = {
 0,1,2,4,5,8,9,24,
 0,1,2,3,4,8,
 0,1,2,3,
 1,2,3,
 0,1,4,5,6,8,9,24,
 0,4,5,6,7,8,
 4,5,6,7,
 5,6,7,
 0,1,4,5,8,9,10,24,
 0,4,8,9,10,11,
 8,9,10,11,12,14,19,
 9,10,11,12,13,14,15,19,20,
 10,11,12,13,14,15,19,20,
 11,12,13,14,19,
 10,11,12,13,14,15,16,19,20,
 11,12,14,15,16,17,19,
 14,15,16,17,18,
 15,16,17,18,
 16,17,18,
 10,11,12,13,14,15,19,20,21,
 11,12,14,19,20,21,22,
 19,20,21,22,23,
 20,21,22,23,
 21,22,23,
 0,4,8,24};
__constant__ int PAIR_A[NPOOL] = {0,2,4,6,8,10,12,14,15,17,19,20,22,24};
__constant__ int PAIR_B[NPOOL] = {1,3,5,7,9,11,13,-1,16,18,-1,21,23,-1};

// joint bins for 4 waves (balanced by deg*8: 288/288/304/280)
__constant__ int WJ[4][7]  = {{11,8,1,9,22,18,0},{14,12,5,13,2,24,0},{19,10,15,16,6,3,23},{0,4,20,21,17,7,0}};
__constant__ int WJN[4]    = {6,6,7,6};
// pool-group bins for 4 waves of final kernel (272/272/320/296)
__constant__ int FG[4][4]  = {{5,7,10,0},{0,6,9,0},{2,8,1,12},{4,11,3,13}};
__constant__ int FGN[4]    = {3,3,4,4};

// ---------------- Kernel P: pre-gather weights into dense per-cl layout ----------
// grid (14, 25, 3), block 256
__global__ void pregather(const float* __restrict__ w0, const float* __restrict__ w1,
                          const float* __restrict__ ws,
                          float* __restrict__ wg0, float* __restrict__ wg1,
                          float* __restrict__ wgs)
{
    const int jo = blockIdx.y, which = blockIdx.z;
    const int idx = blockIdx.x * 256 + threadIdx.x;
    const int off = NBR_OFF[jo];
    const int deg = NBR_OFF[jo + 1] - off;
    const int cl8 = off * 8;
    if (which == 0) {
        int tot = deg * 8 * 24; if (idx >= tot) return;
        int cl = idx / 24; int r = idx - cl * 24; int k = r >> 3; int oc = r & 7;
        int ci = NBR[off + (cl >> 3)] * 8 + (cl & 7);
        wg0[(size_t)(cl8 + cl) * 24 + r] = w0[(size_t)(jo * 8 + oc) * 600 + ci * 3 + k];
    } else if (which == 1) {
        int tot = deg * 8 * 48; if (idx >= tot) return;
        int cl = idx / 48; int r = idx - cl * 48; int k = r >> 4; int oc = r & 15;
        int ci = NBR[off + (cl >> 3)] * 8 + (cl & 7);
        wg1[(size_t)(cl8 + cl) * 48 + r] = w1[(size_t)(jo * 16 + oc) * 600 + ci * 3 + k];
    } else {
        int tot = deg * 8 * 16; if (idx >= tot) return;
        int cl = idx >> 4; int oc = idx & 15;
        int ci = NBR[off + (cl >> 3)] * 8 + (cl & 7);
        wgs[(size_t)(cl8 + cl) * 16 + oc] = ws[(size_t)(jo * 16 + oc) * 200 + ci];
    }
}

// ---------------- Kernel A: conv0 (K=3,s=1,reflect) + PReLU, LDS-tiled ------------
// grid (128, 16), block 256.  tile = 64 t.  LDS 57.6 KB -> 2 blocks/CU
__global__ __launch_bounds__(256) void conv0_t(
    const float* __restrict__ x, const float* __restrict__ wg0,
    const float* __restrict__ b0, const float* __restrict__ a0,
    float* __restrict__ h0)
{
    __shared__ float xs[CIN * 72];
    const int b = blockIdx.y;
    const int t0 = blockIdx.x * 64;
    const int tid = threadIdx.x;
    const float* xb = x + (size_t)b * CIN * T1;

    for (int e = tid; e < CIN * 72; e += 256) {
        int c = e / 72; int i = e - c * 72;
        int gp = t0 - 4 + i;
        gp = (gp < 0) ? -gp : gp;
        gp = (gp >= T1) ? (2 * T1 - 2 - gp) : gp;
        xs[e] = xb[(size_t)c * T1 + gp];
    }
    __syncthreads();

    const int wid  = __builtin_amdgcn_readfirstlane(tid >> 6);
    const int lane = tid & 63;
    const float alpha = a0[0];
    const int nj = WJN[wid];

    for (int jj = 0; jj < nj; ++jj) {
        const int j   = WJ[wid][jj];
        const int off = NBR_OFF[j];
        const int n8  = (NBR_OFF[j + 1] - off) * 8;
        const int cl8 = off * 8;
        float acc[8];
#pragma unroll
        for (int oc = 0; oc < 8; ++oc) acc[oc] = b0[j * 8 + oc];

#pragma unroll 2
        for (int cl = 0; cl < n8; ++cl) {
            int ci = NBR[off + (cl >> 3)] * 8 + (cl & 7);
            const float* xr = xs + ci * 72 + lane;
            float xm = xr[3], x0v = xr[4], xp = xr[5];
            const float4* w4 = (const float4*)(wg0 + (size_t)(cl8 + cl) * 24);
            float wv[24];
#pragma unroll
            for (int q = 0; q < 6; ++q) *(float4*)(wv + 4 * q) = w4[q];
#pragma unroll
            for (int oc = 0; oc < 8; ++oc)
                acc[oc] += wv[oc] * xm + wv[8 + oc] * x0v + wv[16 + oc] * xp;
        }

        float* hb = h0 + ((size_t)b * CIN + j * 8) * T1 + t0 + lane;
#pragma unroll
        for (int oc = 0; oc < 8; ++oc) {
            float v = acc[oc];
            hb[(size_t)oc * T1] = (v >= 0.f) ? v : alpha * v;
        }
    }
}

// ---------------- Kernel B: conv1 (K=3,s=2,reflect), LDS-tiled --------------------
// grid (128, 16), block 256.  tile = 32 t2 (64 t of h0).  lane = (half, t2off)
__global__ __launch_bounds__(256) void conv1_t(
    const float* __restrict__ h0, const float* __restrict__ wg1,
    const float* __restrict__ b1, float* __restrict__ h1)
{
    __shared__ float xs[CIN * 72];
    const int b = blockIdx.y;
    const int t20 = blockIdx.x * 32;
    const int tid = threadIdx.x;
    const float* hb = h0 + (size_t)b * CIN * T1;
    const int p0 = 2 * t20;

    for (int e = tid; e < CIN * 72; e += 256) {
        int c = e / 72; int i = e - c * 72;
        int gp = p0 - 4 + i;
        gp = (gp < 0) ? -gp : gp;
        gp = (gp >= T1) ? (2 * T1 - 2 - gp) : gp;
        xs[e] = hb[(size_t)c * T1 + gp];
    }
    __syncthreads();

    const int wid  = __builtin_amdgcn_readfirstlane(tid >> 6);
    const int lane = tid & 63;
    const int half = lane >> 5;
    const int tq   = lane & 31;
    const int nj = WJN[wid];

    for (int jj = 0; jj < nj; ++jj) {
        const int j   = WJ[wid][jj];
        const int off = NBR_OFF[j];
        const int n8  = (NBR_OFF[j + 1] - off) * 8;
        const int cl8 = off * 8;
        float acc[8];
#pragma unroll
        for (int oc = 0; oc < 8; ++oc) acc[oc] = b1[j * 16 + half * 8 + oc];

#pragma unroll 2
        for (int cl = 0; cl < n8; ++cl) {
            int ci = NBR[off + (cl >> 3)] * 8 + (cl & 7);
            const float* xr = xs + ci * 72 + 2 * tq;
            float xm = xr[3], x0v = xr[4], xp = xr[5];
            const float4* w4 = (const float4*)(wg1 + (size_t)(cl8 + cl) * 48 + half * 8);
            float wv[24];
            *(float4*)(wv +  0) = w4[0]; *(float4*)(wv +  4) = w4[1];
            *(float4*)(wv +  8) = w4[4]; *(float4*)(wv + 12) = w4[5];
            *(float4*)(wv + 16) = w4[8]; *(float4*)(wv + 20) = w4[9];
#pragma unroll
            for (int oc = 0; oc < 8; ++oc)
                acc[oc] += wv[oc] * xm + wv[8 + oc] * x0v + wv[16 + oc] * xp;
        }

        float* ob = h1 + ((size_t)b * COUTC + j * 16 + half * 8) * TT2 + t20 + tq;
#pragma unroll
        for (int oc = 0; oc < 8; ++oc) ob[(size_t)oc * TT2] = acc[oc];
    }
}

// ---------------- Kernel C: GroupNorm partial sums --------------------------------
// grid (32, 10, 16), block 256
__global__ __launch_bounds__(256) void gn_part(
    const float* __restrict__ h1, float* __restrict__ part)
{
    const int sl = blockIdx.x, g = blockIdx.y, b = blockIdx.z;
    const int tid = threadIdx.x;
    const int t0 = sl * (TT2 / 32);

    const float* base = h1 + (size_t)b * COUTC * TT2 + (size_t)g * CPG * TT2;
    float s = 0.f, ss = 0.f;
    for (int i = tid; i < CPG * 32; i += 256) {
        int c  = i >> 5;
        int t4 = i & 31;
        float4 v = *(const float4*)(base + (size_t)c * TT2 + t0 + 4 * t4);
        s  += v.x + v.y + v.z + v.w;
        ss += v.x * v.x + v.y * v.y + v.z * v.z + v.w * v.w;
    }
    for (int o = 32; o; o >>= 1) {
        s  += __shfl_down(s, o, 64);
        ss += __shfl_down(ss, o, 64);
    }
    __shared__ float rs[4], rss[4];
    const int lane = tid & 63, wv = tid >> 6;
    if (lane == 0) { rs[wv] = s; rss[wv] = ss; }
    __syncthreads();
    if (tid == 0) {
        float S  = rs[0] + rs[1] + rs[2] + rs[3];
        float SS = rss[0] + rss[1] + rss[2] + rss[3];
        size_t o = (((size_t)b * NGROUP + g) * 32 + sl) * 2;
        part[o] = S;
        part[o + 1] = SS;
    }
}

// ---------------- Kernel D: finalize stats ----------------------------------------
__global__ void gn_final(const float* __restrict__ part, float* __restrict__ stats)
{
    int i = threadIdx.x;
    if (i < BATCH * NGROUP) {
        float s = 0.f, ss = 0.f;
        for (int k = 0; k < 32; ++k) {
            s  += part[((size_t)i * 32 + k) * 2];
            ss += part[((size_t)i * 32 + k) * 2 + 1];
        }
        const float invN = 1.0f / (float)(CPG * TT2);
        float mean = s * invN;
        float var  = ss * invN - mean * mean;
        stats[i * 2]     = mean;
        stats[i * 2 + 1] = rsqrtf(var + 1e-5f);
    }
}

// ---------------- Kernel D2: per-(b,ch) GN coefficients ---------------------------
// grid (25), block 256
__global__ void gn_coef(const float* __restrict__ stats, const float* __restrict__ gamma,
                        const float* __restrict__ beta, float* __restrict__ AB)
{
    int idx = blockIdx.x * 256 + threadIdx.x;
    if (idx < BATCH * COUTC) {
        int b = idx / COUTC; int ch = idx - b * COUTC;
        int g = ch / CPG;
        float m = stats[(b * NGROUP + g) * 2];
        float r = stats[(b * NGROUP + g) * 2 + 1];
        float A = r * gamma[ch];
        AB[(size_t)idx * 2]     = A;
        AB[(size_t)idx * 2 + 1] = beta[ch] - m * A;
    }
}

// ---------------- Kernel E: fused shortcut + GN-apply + pool + PReLU --------------
// grid (64, 16), block 256.  tile = 64 t2.  LDS 51.2 KB
__global__ __launch_bounds__(256) void final_t(
    const float* __restrict__ x, const float* __restrict__ h1,
    const float* __restrict__ wgs, const float* __restrict__ bs,
    const float* __restrict__ AB, const float* __restrict__ a1,
    float* __restrict__ out)
{
    __shared__ float xs[CIN * 64];
    const int b = blockIdx.y;
    const int t20 = blockIdx.x * 64;
    const int tid = threadIdx.x;
    const float* xb = x + (size_t)b * CIN * T1;

    for (int e = tid; e < CIN * 32; e += 256) {
        int c = e >> 5; int q = e & 31;
        float4 v = *(const float4*)(xb + (size_t)c * T1 + 2 * t20 + 4 * q);
        float2 pr; pr.x = v.x; pr.y = v.z;
        *(float2*)(xs + c * 64 + 2 * q) = pr;
    }
    __syncthreads();

    const int wid  = __builtin_amdgcn_readfirstlane(tid >> 6);
    const int lane = tid & 63;
    const float alpha = a1[0];
    const float* h1b = h1 + (size_t)b * COUTC * TT2 + t20 + lane;
    const float* ABb = AB + (size_t)b * COUTC * 2;
    const int ng = FGN[wid];

    for (int gi = 0; gi < ng; ++gi) {
        const int n   = FG[wid][gi];
        const int ja  = PAIR_A[n];
        const int jb2 = PAIR_B[n];
        const int L   = (jb2 >= 0) ? 2 : 1;
        float outacc[16];
#pragma unroll
        for (int c = 0; c < 16; ++c) outacc[c] = 0.f;

        for (int ji = 0; ji < L; ++ji) {
            const int j   = (ji == 0) ? ja : jb2;
            const int off = NBR_OFF[j];
            const int n8  = (NBR_OFF[j + 1] - off) * 8;
            const int cl8 = off * 8;
            float sacc[16];
#pragma unroll
            for (int c = 0; c < 16; ++c) sacc[c] = bs[j * 16 + c];

#pragma unroll 2
            for (int cl = 0; cl < n8; ++cl) {
                int ci = NBR[off + (cl >> 3)] * 8 + (cl & 7);
                float xv = xs[ci * 64 + lane];
                const float4* w4 = (const float4*)(wgs + (size_t)(cl8 + cl) * 16);
                float wv[16];
#pragma unroll
                for (int q = 0; q < 4; ++q) *(float4*)(wv + 4 * q) = w4[q];
#pragma unroll
                for (int c = 0; c < 16; ++c) sacc[c] += wv[c] * xv;
            }
#pragma unroll
            for (int c = 0; c < 16; ++c) {
                float hv = h1b[(size_t)(j * 16 + c) * TT2];
                float A  = ABb[(j * 16 + c) * 2];
                float Bc = ABb[(j * 16 + c) * 2 + 1];
                outacc[c] += hv * A + Bc + sacc[c];
            }
        }

        const float invL = (L == 2) ? 0.5f : 1.0f;
        float* ob = out + ((size_t)b * 224 + n * 16) * TT2 + t20 + lane;
#pragma unroll
        for (int c = 0; c < 16; ++c) {
            float v = outacc[c] * invL;
            ob[(size_t)c * TT2] = (v >= 0.f) ? v : alpha * v;
        }
    }
}

extern "C" void kernel_launch(void* const* d_in, const int* in_sizes, int n_in,
                              void* d_out, int out_size, void* d_ws, size_t ws_size,
                              hipStream_t stream) {
    const float* x     = (const float*)d_in[0];
    const float* w0    = (const float*)d_in[1];
    const float* b0    = (const float*)d_in[2];
    const float* a0    = (const float*)d_in[3];
    const float* w1    = (const float*)d_in[4];
    const float* b1    = (const float*)d_in[5];
    const float* gamma = (const float*)d_in[6];
    const float* beta  = (const float*)d_in[7];
    const float* ws    = (const float*)d_in[8];
    const float* bs    = (const float*)d_in[9];
    const float* a1    = (const float*)d_in[10];
    float* out = (float*)d_out;

    float* h0    = (float*)d_ws;                            // 26,214,400
    float* h1    = h0 + (size_t)BATCH * CIN * T1;           // 26,214,400
    float* part  = h1 + (size_t)BATCH * COUTC * TT2;        // 10,240
    float* stats = part + (size_t)BATCH * NGROUP * 32 * 2;  // 320
    float* AB    = stats + BATCH * NGROUP * 2;              // 12,800
    float* wg0   = AB + (size_t)BATCH * COUTC * 2;          // 27,840
    float* wg1   = wg0 + 1160 * 24;                         // 55,680
    float* wgs   = wg1 + 1160 * 48;                         // 18,560

    pregather<<<dim3(14, NJ, 3), 256, 0, stream>>>(w0, w1, ws, wg0, wg1, wgs);
    conv0_t<<<dim3(T1 / 64, BATCH), 256, 0, stream>>>(x, wg0, b0, a0, h0);
    conv1_t<<<dim3(TT2 / 32, BATCH), 256, 0, stream>>>(h0, wg1, b1, h1);
    gn_part<<<dim3(32, NGROUP, BATCH), 256, 0, stream>>>(h1, part);
    gn_final<<<1, 256, 0, stream>>>(part, stats);
    gn_coef<<<dim3(25), 256, 0, stream>>>(stats, gamma, beta, AB);
    final_t<<<dim3(TT2 / 64, BATCH), 256, 0, stream>>>(x, h1, wgs, bs, AB, a1, out);
}

// Round 5
// 466.967 us; speedup vs baseline: 2.1687x; 2.1687x over previous
//
#include <hip/hip_runtime.h>

#define BATCH 16
#define CIN   200
#define T1    8192
#define COUTC 400
#define TT2   4096
#define NJ    25
#define NGROUP 10
#define CPG   40
#define NPOOL 14

__constant__ int NBR_OFF[NJ + 1] = {0,8,14,18,21,29,35,39,42,50,56,63,72,80,85,94,101,106,110,113,122,129,134,138,141,145};
__constant__ int NBR[145] = {
 0,1,2,4,5,8,9,24,
 0,1,2,3,4,8,
 0,1,2,3,
 1,2,3,
 0,1,4,5,6,8,9,24,
 0,4,5,6,7,8,
 4,5,6,7,
 5,6,7,
 0,1,4,5,8,9,10,24,
 0,4,8,9,10,11,
 8,9,10,11,12,14,19,
 9,10,11,12,13,14,15,19,20,
 10,11,12,13,14,15,19,20,
 11,12,13,14,19,
 10,11,12,13,14,15,16,19,20,
 11,12,14,15,16,17,19,
 14,15,16,17,18,
 15,16,17,18,
 16,17,18,
 10,11,12,13,14,15,19,20,21,
 11,12,14,19,20,21,22,
 19,20,21,22,23,
 20,21,22,23,
 21,22,23,
 0,4,8,24};
__constant__ int PAIR_A[NPOOL] = {0,2,4,6,8,10,12,14,15,17,19,20,22,24};
__constant__ int PAIR_B[NPOOL] = {1,3,5,7,9,11,13,-1,16,18,-1,21,23,-1};

// ------- Kernel A: conv0 (K=3,s=1,reflect)+PReLU + pooled shortcut (K=1,s=2) -----
// grid (8, 14, 16), block 256, 4 t/thread. h0:(B,200,8192); spooled -> out
__global__ __launch_bounds__(256) void conv0scp(
    const float* __restrict__ x, const float* __restrict__ w0,
    const float* __restrict__ b0, const float* __restrict__ a0,
    const float* __restrict__ wsc, const float* __restrict__ bsc,
    float* __restrict__ h0, float* __restrict__ outb)
{
    const int n   = blockIdx.y;
    const int b   = blockIdx.z;
    const int tid = threadIdx.x;
    const int t0  = (blockIdx.x * 256 + tid) * 4;

    const int ja = PAIR_A[n], jb = PAIR_B[n];
    const int L  = (jb >= 0) ? 2 : 1;

    __shared__ float wl[2][72 * 24];   // conv0 weights [cl][k][oc]
    __shared__ float wsl[2][72 * 16];  // shortcut weights [cl][c]
    __shared__ int   cil[2][72];
    __shared__ float bl[2][8];

    for (int ji = 0; ji < L; ++ji) {
        const int j   = ji ? jb : ja;
        const int off = NBR_OFF[j];
        const int n8  = (NBR_OFF[j + 1] - off) * 8;
        for (int i = tid; i < n8; i += 256)
            cil[ji][i] = NBR[off + (i >> 3)] * 8 + (i & 7);
        for (int idx = tid; idx < n8 * 24; idx += 256) {
            int cl = idx / 24; int r = idx - cl * 24; int k = r >> 3; int oc = r & 7;
            int ci = NBR[off + (cl >> 3)] * 8 + (cl & 7);
            wl[ji][idx] = w0[(size_t)(j * 8 + oc) * 600 + ci * 3 + k];
        }
        for (int idx = tid; idx < n8 * 16; idx += 256) {
            int cl = idx >> 4; int c = idx & 15;
            int ci = NBR[off + (cl >> 3)] * 8 + (cl & 7);
            wsl[ji][idx] = wsc[(size_t)(j * 16 + c) * 200 + ci];
        }
        if (tid < 8) bl[ji][tid] = b0[j * 8 + tid];
    }
    __syncthreads();

    const float alpha = a0[0];
    const bool first = (t0 == 0);
    const bool last  = (t0 + 4 == T1);
    const float* xb = x + (size_t)b * CIN * T1;

    float sacc[16][2];
#pragma unroll
    for (int c = 0; c < 16; ++c) {
        float bsum = bsc[ja * 16 + c] + ((L == 2) ? bsc[jb * 16 + c] : 0.f);
        sacc[c][0] = bsum; sacc[c][1] = bsum;
    }

    for (int ji = 0; ji < L; ++ji) {
        const int j  = ji ? jb : ja;
        const int n8 = (NBR_OFF[j + 1] - NBR_OFF[j]) * 8;
        float acc[8][4];
#pragma unroll
        for (int oc = 0; oc < 8; ++oc) {
            float bv = bl[ji][oc];
            acc[oc][0] = bv; acc[oc][1] = bv; acc[oc][2] = bv; acc[oc][3] = bv;
        }

        for (int cl = 0; cl < n8; ++cl) {
            const float* xc = xb + (size_t)cil[ji][cl] * T1;
            float4 v = *(const float4*)(xc + t0);
            float xs[6];
            xs[1] = v.x; xs[2] = v.y; xs[3] = v.z; xs[4] = v.w;
            xs[0] = first ? v.y : xc[t0 - 1];
            xs[5] = last  ? v.z : xc[t0 + 4];

            float wv[24];
            const float4* w4 = (const float4*)(&wl[ji][cl * 24]);
#pragma unroll
            for (int q = 0; q < 6; ++q) *(float4*)(wv + 4 * q) = w4[q];
#pragma unroll
            for (int oc = 0; oc < 8; ++oc) {
                float wa = wv[oc], wb = wv[8 + oc], wc = wv[16 + oc];
#pragma unroll
                for (int i = 0; i < 4; ++i)
                    acc[oc][i] += wa * xs[i] + wb * xs[i + 1] + wc * xs[i + 2];
            }

            float wsv[16];
            const float4* ws4 = (const float4*)(&wsl[ji][cl * 16]);
#pragma unroll
            for (int q = 0; q < 4; ++q) *(float4*)(wsv + 4 * q) = ws4[q];
#pragma unroll
            for (int c = 0; c < 16; ++c) {
                sacc[c][0] += wsv[c] * v.x;
                sacc[c][1] += wsv[c] * v.z;
            }
        }

        float* hb = h0 + ((size_t)b * CIN + j * 8) * T1 + t0;
#pragma unroll
        for (int oc = 0; oc < 8; ++oc) {
            float4 o;
            o.x = acc[oc][0] >= 0.f ? acc[oc][0] : alpha * acc[oc][0];
            o.y = acc[oc][1] >= 0.f ? acc[oc][1] : alpha * acc[oc][1];
            o.z = acc[oc][2] >= 0.f ? acc[oc][2] : alpha * acc[oc][2];
            o.w = acc[oc][3] >= 0.f ? acc[oc][3] : alpha * acc[oc][3];
            *(float4*)(hb + (size_t)oc * T1) = o;
        }
    }

    // pooled (unscaled-sum) shortcut -> out buffer
    const int t2 = t0 >> 1;
    float* ob = outb + ((size_t)b * 224 + n * 16) * TT2 + t2;
#pragma unroll
    for (int c = 0; c < 16; ++c)
        *(float2*)(ob + (size_t)c * TT2) = make_float2(sacc[c][0], sacc[c][1]);
}

// ------- Kernel B: conv1 (K=3,s=2,reflect) + GN partials, 8t x 8oc ---------------
// grid (4, 25, 16), block 256.  h1:(B,400,4096); part[b][50][4][2]
__global__ __launch_bounds__(256) void conv1_gn8(
    const float* __restrict__ h0, const float* __restrict__ w1,
    const float* __restrict__ b1, float* __restrict__ h1,
    float* __restrict__ part)
{
    const int jo   = blockIdx.y;
    const int b    = blockIdx.z;
    const int tid  = threadIdx.x;
    const int half = tid >> 7;
    const int tl   = tid & 127;
    const int t0   = blockIdx.x * 1024 + tl * 8;   // t2 units

    const int off = NBR_OFF[jo];
    const int n8  = (NBR_OFF[jo + 1] - off) * 8;

    __shared__ float wl[72 * 48];   // [cl][k][16oc]
    __shared__ int   cil[72];
    __shared__ float red[4][2];

    for (int i = tid; i < n8; i += 256)
        cil[i] = NBR[off + (i >> 3)] * 8 + (i & 7);
    for (int idx = tid; idx < n8 * 48; idx += 256) {
        int cl = idx / 48; int r = idx - cl * 48; int k = r >> 4; int oc = r & 15;
        int ci = NBR[off + (cl >> 3)] * 8 + (cl & 7);
        wl[idx] = w1[(size_t)(jo * 16 + oc) * 600 + ci * 3 + k];
    }
    __syncthreads();

    float acc[8][8];
#pragma unroll
    for (int oc = 0; oc < 8; ++oc) {
        float bv = b1[jo * 16 + half * 8 + oc];
#pragma unroll
        for (int i = 0; i < 8; ++i) acc[oc][i] = bv;
    }

    const int p = 2 * t0;
    const bool first = (p == 0);
    const float* hb = h0 + (size_t)b * CIN * T1;

    for (int cl = 0; cl < n8; ++cl) {
        const float* xc = hb + (size_t)cil[cl] * T1;
        float4 A0 = *(const float4*)(xc + p);
        float4 A1 = *(const float4*)(xc + p + 4);
        float4 A2 = *(const float4*)(xc + p + 8);
        float4 A3 = *(const float4*)(xc + p + 12);
        float xr[17];
        xr[0] = first ? A0.y : xc[p - 1];
        xr[1] = A0.x;  xr[2] = A0.y;  xr[3] = A0.z;  xr[4] = A0.w;
        xr[5] = A1.x;  xr[6] = A1.y;  xr[7] = A1.z;  xr[8] = A1.w;
        xr[9] = A2.x;  xr[10] = A2.y; xr[11] = A2.z; xr[12] = A2.w;
        xr[13] = A3.x; xr[14] = A3.y; xr[15] = A3.z; xr[16] = A3.w;

        float wv[24];
        const float* wb = &wl[cl * 48 + half * 8];
        *(float4*)(wv + 0)  = *(const float4*)(wb + 0);
        *(float4*)(wv + 4)  = *(const float4*)(wb + 4);
        *(float4*)(wv + 8)  = *(const float4*)(wb + 16);
        *(float4*)(wv + 12) = *(const float4*)(wb + 20);
        *(float4*)(wv + 16) = *(const float4*)(wb + 32);
        *(float4*)(wv + 20) = *(const float4*)(wb + 36);
#pragma unroll
        for (int oc = 0; oc < 8; ++oc) {
            float wa = wv[oc], wq = wv[8 + oc], wc = wv[16 + oc];
#pragma unroll
            for (int i = 0; i < 8; ++i)
                acc[oc][i] += wa * xr[2 * i] + wq * xr[2 * i + 1] + wc * xr[2 * i + 2];
        }
    }

    float* ob = h1 + ((size_t)b * COUTC + jo * 16 + half * 8) * TT2 + t0;
#pragma unroll
    for (int oc = 0; oc < 8; ++oc) {
        *(float4*)(ob + (size_t)oc * TT2)     = make_float4(acc[oc][0], acc[oc][1], acc[oc][2], acc[oc][3]);
        *(float4*)(ob + (size_t)oc * TT2 + 4) = make_float4(acc[oc][4], acc[oc][5], acc[oc][6], acc[oc][7]);
    }

    // GN partials for sub-block sb = jo*2 + half
    float s = 0.f, ss = 0.f;
#pragma unroll
    for (int oc = 0; oc < 8; ++oc)
#pragma unroll
        for (int i = 0; i < 8; ++i) { float v = acc[oc][i]; s += v; ss += v * v; }
    for (int o = 32; o; o >>= 1) {
        s  += __shfl_down(s, o, 64);
        ss += __shfl_down(ss, o, 64);
    }
    const int lane = tid & 63, wv2 = tid >> 6;
    if (lane == 0) { red[wv2][0] = s; red[wv2][1] = ss; }
    __syncthreads();
    if (tid == 0) {
        size_t o = (((size_t)b * 50 + jo * 2 + 0) * 4 + blockIdx.x) * 2;
        part[o] = red[0][0] + red[1][0];
        part[o + 1] = red[0][1] + red[1][1];
    }
    if (tid == 128) {
        size_t o = (((size_t)b * 50 + jo * 2 + 1) * 4 + blockIdx.x) * 2;
        part[o] = red[2][0] + red[3][0];
        part[o + 1] = red[2][1] + red[3][1];
    }
}

// ------- Kernel C: finalize stats -------------------------------------------------
__global__ void gn_final(const float* __restrict__ part, float* __restrict__ stats)
{
    int i = threadIdx.x;
    if (i < BATCH * NGROUP) {
        int b = i / NGROUP, g = i % NGROUP;
        float s = 0.f, ss = 0.f;
        for (int sb = 0; sb < 5; ++sb)
            for (int xb = 0; xb < 4; ++xb) {
                size_t o = (((size_t)b * 50 + g * 5 + sb) * 4 + xb) * 2;
                s  += part[o];
                ss += part[o + 1];
            }
        const float invN = 1.0f / (float)(CPG * TT2);
        float mean = s * invN;
        float var  = ss * invN - mean * mean;
        stats[i * 2]     = mean;
        stats[i * 2 + 1] = rsqrtf(var + 1e-5f);
    }
}

// ------- Kernel D: per-(b,ch) GN coefficients ------------------------------------
__global__ void gn_coef(const float* __restrict__ stats, const float* __restrict__ gamma,
                        const float* __restrict__ beta, float* __restrict__ AB)
{
    int idx = blockIdx.x * 256 + threadIdx.x;
    if (idx < BATCH * COUTC) {
        int b = idx / COUTC; int ch = idx - b * COUTC;
        int g = ch / CPG;
        float m = stats[(b * NGROUP + g) * 2];
        float r = stats[(b * NGROUP + g) * 2 + 1];
        float A = r * gamma[ch];
        AB[(size_t)idx * 2]     = A;
        AB[(size_t)idx * 2 + 1] = beta[ch] - m * A;
    }
}

// ------- Kernel E: streaming GN-apply + pool + add spooled + PReLU ---------------
// grid (4, 28, 16), block 256, 4 t2/thread
__global__ __launch_bounds__(256) void final2p(
    const float* __restrict__ h1, const float* __restrict__ AB,
    const float* __restrict__ a1, float* __restrict__ outb)
{
    const int n     = blockIdx.y >> 1;
    const int chalf = blockIdx.y & 1;
    const int b     = blockIdx.z;
    const int tid   = threadIdx.x;
    const int t0    = (blockIdx.x * 256 + tid) * 4;

    int js[2];
    js[0] = PAIR_A[n];
    const int jb = PAIR_B[n];
    const int L = (jb >= 0) ? 2 : 1;
    js[1] = (jb >= 0) ? jb : js[0];

    __shared__ float Al[2][8], Bl[2][8];
    if (tid < 16) {
        int ji = tid >> 3, c8 = tid & 7;
        int ch = js[ji] * 16 + chalf * 8 + c8;
        Al[ji][c8] = AB[((size_t)b * COUTC + ch) * 2];
        Bl[ji][c8] = AB[((size_t)b * COUTC + ch) * 2 + 1];
    }
    __syncthreads();

    const float alpha = a1[0];
    const float invL  = (L == 2) ? 0.5f : 1.0f;
    const float* h1b = h1 + (size_t)b * COUTC * TT2;

    float acc[8][4];
#pragma unroll
    for (int c = 0; c < 8; ++c)
#pragma unroll
        for (int i = 0; i < 4; ++i) acc[c][i] = 0.f;

    for (int ji = 0; ji < L; ++ji) {
        const int jc0 = js[ji] * 16 + chalf * 8;
#pragma unroll
        for (int c = 0; c < 8; ++c) {
            float4 hv = *(const float4*)(h1b + (size_t)(jc0 + c) * TT2 + t0);
            float A = Al[ji][c], Bc = Bl[ji][c];
            acc[c][0] += hv.x * A + Bc;
            acc[c][1] += hv.y * A + Bc;
            acc[c][2] += hv.z * A + Bc;
            acc[c][3] += hv.w * A + Bc;
        }
    }

    float* ob = outb + ((size_t)b * 224 + n * 16 + chalf * 8) * TT2 + t0;
#pragma unroll
    for (int c = 0; c < 8; ++c) {
        float4 sv = *(const float4*)(ob + (size_t)c * TT2);   // spooled from conv0scp
        float4 o;
        float v0 = (acc[c][0] + sv.x) * invL; o.x = v0 >= 0.f ? v0 : alpha * v0;
        float v1 = (acc[c][1] + sv.y) * invL; o.y = v1 >= 0.f ? v1 : alpha * v1;
        float v2 = (acc[c][2] + sv.z) * invL; o.z = v2 >= 0.f ? v2 : alpha * v2;
        float v3 = (acc[c][3] + sv.w) * invL; o.w = v3 >= 0.f ? v3 : alpha * v3;
        *(float4*)(ob + (size_t)c * TT2) = o;
    }
}

extern "C" void kernel_launch(void* const* d_in, const int* in_sizes, int n_in,
                              void* d_out, int out_size, void* d_ws, size_t ws_size,
                              hipStream_t stream) {
    const float* x     = (const float*)d_in[0];
    const float* w0    = (const float*)d_in[1];
    const float* b0    = (const float*)d_in[2];
    const float* a0    = (const float*)d_in[3];
    const float* w1    = (const float*)d_in[4];
    const float* b1    = (const float*)d_in[5];
    const float* gamma = (const float*)d_in[6];
    const float* beta  = (const float*)d_in[7];
    const float* wsc   = (const float*)d_in[8];
    const float* bsc   = (const float*)d_in[9];
    const float* a1    = (const float*)d_in[10];
    float* out = (float*)d_out;

    float* h0    = (float*)d_ws;                            // 26,214,400 floats
    float* h1    = h0 + (size_t)BATCH * CIN * T1;           // 26,214,400 floats
    float* part  = h1 + (size_t)BATCH * COUTC * TT2;        // 6,400 floats
    float* stats = part + (size_t)BATCH * 50 * 4 * 2;       // 320 floats
    float* AB    = stats + BATCH * NGROUP * 2;              // 12,800 floats

    conv0scp<<<dim3(T1 / 1024, NPOOL, BATCH), 256, 0, stream>>>(x, w0, b0, a0, wsc, bsc, h0, out);
    conv1_gn8<<<dim3(TT2 / 1024, NJ, BATCH), 256, 0, stream>>>(h0, w1, b1, h1, part);
    gn_final<<<1, 256, 0, stream>>>(part, stats);
    gn_coef<<<dim3(25), 256, 0, stream>>>(stats, gamma, beta, AB);
    final2p<<<dim3(TT2 / 1024, NPOOL * 2, BATCH), 256, 0, stream>>>(h1, AB, a1, out);
}

// Round 6
// 445.311 us; speedup vs baseline: 2.2741x; 1.0486x over previous
//
#include <hip/hip_runtime.h>

#define BATCH 16
#define CIN   200
#define T1    8192
#define COUTC 400
#define TT2   4096
#define NJ    25
#define NGROUP 10
#define CPG   40
#define NPOOL 14

__constant__ int NBR_OFF[NJ + 1] = {0,8,14,18,21,29,35,39,42,50,56,63,72,80,85,94,101,106,110,113,122,129,134,138,141,145};
__constant__ int NBR[145] = {
 0,1,2,4,5,8,9,24,
 0,1,2,3,4,8,
 0,1,2,3,
 1,2,3,
 0,1,4,5,6,8,9,24,
 0,4,5,6,7,8,
 4,5,6,7,
 5,6,7,
 0,1,4,5,8,9,10,24,
 0,4,8,9,10,11,
 8,9,10,11,12,14,19,
 9,10,11,12,13,14,15,19,20,
 10,11,12,13,14,15,19,20,
 11,12,13,14,19,
 10,11,12,13,14,15,16,19,20,
 11,12,14,15,16,17,19,
 14,15,16,17,18,
 15,16,17,18,
 16,17,18,
 10,11,12,13,14,15,19,20,21,
 11,12,14,19,20,21,22,
 19,20,21,22,23,
 20,21,22,23,
 21,22,23,
 0,4,8,24};
__constant__ int PAIR_A[NPOOL] = {0,2,4,6,8,10,12,14,15,17,19,20,22,24};
__constant__ int PAIR_B[NPOOL] = {1,3,5,7,9,11,13,-1,16,18,-1,21,23,-1};

// ---- bf16 helpers (RNE pack, shift unpack) ----
__device__ __forceinline__ unsigned bfround(float f) {
    unsigned u = __builtin_bit_cast(unsigned, f);
    return (u + 0x7FFFu + ((u >> 16) & 1u)) >> 16;
}
__device__ __forceinline__ unsigned packbf(float lo, float hi) {
    return bfround(lo) | (bfround(hi) << 16);
}
__device__ __forceinline__ float bflo(unsigned u) { return __builtin_bit_cast(float, u << 16); }
__device__ __forceinline__ float bfhi(unsigned u) { return __builtin_bit_cast(float, u & 0xFFFF0000u); }

// ------- Kernel A: conv0 (K=3,s=1,reflect)+PReLU + per-joint shortcut (K=1,s=2) --
// grid (4, 25, 16), block 256, 8 t/thread.  h0b bf16 (B,200,8192); sb bf16 (B,400,4096)
__global__ __launch_bounds__(256) void conv0j(
    const float* __restrict__ x, const float* __restrict__ w0,
    const float* __restrict__ b0, const float* __restrict__ a0,
    const float* __restrict__ wsc, const float* __restrict__ bsc,
    unsigned* __restrict__ h0b, unsigned* __restrict__ sb)
{
    const int jo  = blockIdx.y;
    const int b   = blockIdx.z;
    const int tid = threadIdx.x;
    const int t0  = blockIdx.x * 2048 + tid * 8;

    const int off = NBR_OFF[jo];
    const int n8  = (NBR_OFF[jo + 1] - off) * 8;

    __shared__ float wl[72 * 24];    // conv0 weights [cl][k][oc]
    __shared__ float wsl[72 * 16];   // shortcut weights [cl][c]
    __shared__ int   cil[72];
    __shared__ float bl[8], bsl[16];

    for (int i = tid; i < n8; i += 256)
        cil[i] = NBR[off + (i >> 3)] * 8 + (i & 7);
    for (int idx = tid; idx < n8 * 24; idx += 256) {
        int cl = idx / 24; int r = idx - cl * 24; int k = r >> 3; int oc = r & 7;
        int ci = NBR[off + (cl >> 3)] * 8 + (cl & 7);
        wl[idx] = w0[(size_t)(jo * 8 + oc) * 600 + ci * 3 + k];
    }
    for (int idx = tid; idx < n8 * 16; idx += 256) {
        int cl = idx >> 4; int c = idx & 15;
        int ci = NBR[off + (cl >> 3)] * 8 + (cl & 7);
        wsl[idx] = wsc[(size_t)(jo * 16 + c) * 200 + ci];
    }
    if (tid < 8)  bl[tid]  = b0[jo * 8 + tid];
    if (tid < 16) bsl[tid] = bsc[jo * 16 + tid];
    __syncthreads();

    const float alpha = a0[0];
    const bool first = (t0 == 0);
    const bool last  = (t0 + 8 == T1);
    const float* xb = x + (size_t)b * CIN * T1;

    float acc[8][8];
#pragma unroll
    for (int oc = 0; oc < 8; ++oc) {
        float bv = bl[oc];
#pragma unroll
        for (int i = 0; i < 8; ++i) acc[oc][i] = bv;
    }
    float sacc[16][4];
#pragma unroll
    for (int c = 0; c < 16; ++c) {
        float bv = bsl[c];
#pragma unroll
        for (int q = 0; q < 4; ++q) sacc[c][q] = bv;
    }

    for (int cl = 0; cl < n8; ++cl) {
        const float* xc = xb + (size_t)cil[cl] * T1;
        float4 v0 = *(const float4*)(xc + t0);
        float4 v1 = *(const float4*)(xc + t0 + 4);
        float xr[10];
        xr[1] = v0.x; xr[2] = v0.y; xr[3] = v0.z; xr[4] = v0.w;
        xr[5] = v1.x; xr[6] = v1.y; xr[7] = v1.z; xr[8] = v1.w;
        xr[0] = first ? xr[2] : xc[t0 - 1];
        xr[9] = last  ? xr[7] : xc[t0 + 8];

        float wv[24];
        const float4* w4 = (const float4*)(&wl[cl * 24]);
#pragma unroll
        for (int q = 0; q < 6; ++q) *(float4*)(wv + 4 * q) = w4[q];
#pragma unroll
        for (int oc = 0; oc < 8; ++oc) {
            float wa = wv[oc], wb = wv[8 + oc], wc = wv[16 + oc];
#pragma unroll
            for (int i = 0; i < 8; ++i)
                acc[oc][i] += wa * xr[i] + wb * xr[i + 1] + wc * xr[i + 2];
        }

        float wsv[16];
        const float4* ws4 = (const float4*)(&wsl[cl * 16]);
#pragma unroll
        for (int q = 0; q < 4; ++q) *(float4*)(wsv + 4 * q) = ws4[q];
#pragma unroll
        for (int c = 0; c < 16; ++c) {
            float w = wsv[c];
#pragma unroll
            for (int q = 0; q < 4; ++q) sacc[c][q] += w * xr[1 + 2 * q];
        }
    }

    // h0 write: prelu + bf16 pack (8 rows × 8 t = 1 uint4 per row)
    unsigned* hb = h0b + ((size_t)b * CIN + jo * 8) * (T1 / 2) + t0 / 2;
#pragma unroll
    for (int oc = 0; oc < 8; ++oc) {
        float v[8];
#pragma unroll
        for (int i = 0; i < 8; ++i) {
            float a = acc[oc][i];
            v[i] = (a >= 0.f) ? a : alpha * a;
        }
        uint4 o;
        o.x = packbf(v[0], v[1]); o.y = packbf(v[2], v[3]);
        o.z = packbf(v[4], v[5]); o.w = packbf(v[6], v[7]);
        *(uint4*)(hb + (size_t)oc * (T1 / 2)) = o;
    }

    // shortcut write (unpooled, this joint's 16 rows, 4 t2 = uint2)
    unsigned* sbp = sb + ((size_t)b * COUTC + jo * 16) * (TT2 / 2) + t0 / 4;
#pragma unroll
    for (int c = 0; c < 16; ++c) {
        uint2 o;
        o.x = packbf(sacc[c][0], sacc[c][1]);
        o.y = packbf(sacc[c][2], sacc[c][3]);
        *(uint2*)(sbp + (size_t)c * (TT2 / 2)) = o;
    }
}

// ------- Kernel B: conv1 (K=3,s=2,reflect) + GN partials, bf16 in/out ------------
// grid (4, 25, 16), block 256.  h1b bf16 (B,400,4096); part[b][50][4][2]
__global__ __launch_bounds__(256) void conv1_gn8b(
    const unsigned* __restrict__ h0b, const float* __restrict__ w1,
    const float* __restrict__ b1, unsigned* __restrict__ h1b,
    float* __restrict__ part)
{
    const int jo   = blockIdx.y;
    const int b    = blockIdx.z;
    const int tid  = threadIdx.x;
    const int half = tid >> 7;
    const int tl   = tid & 127;
    const int t0   = blockIdx.x * 1024 + tl * 8;   // t2 units

    const int off = NBR_OFF[jo];
    const int n8  = (NBR_OFF[jo + 1] - off) * 8;

    __shared__ float wl[72 * 48];   // [cl][k][16oc]
    __shared__ int   cil[72];
    __shared__ float red[4][2];

    for (int i = tid; i < n8; i += 256)
        cil[i] = NBR[off + (i >> 3)] * 8 + (i & 7);
    for (int idx = tid; idx < n8 * 48; idx += 256) {
        int cl = idx / 48; int r = idx - cl * 48; int k = r >> 4; int oc = r & 15;
        int ci = NBR[off + (cl >> 3)] * 8 + (cl & 7);
        wl[idx] = w1[(size_t)(jo * 16 + oc) * 600 + ci * 3 + k];
    }
    __syncthreads();

    float acc[8][8];
#pragma unroll
    for (int oc = 0; oc < 8; ++oc) {
        float bv = b1[jo * 16 + half * 8 + oc];
#pragma unroll
        for (int i = 0; i < 8; ++i) acc[oc][i] = bv;
    }

    const bool first = (t0 == 0);
    const unsigned* hb = h0b + (size_t)b * CIN * (T1 / 2);

    for (int cl = 0; cl < n8; ++cl) {
        const unsigned* xc = hb + (size_t)cil[cl] * (T1 / 2);
        uint4 U0 = *(const uint4*)(xc + t0);
        uint4 U1 = *(const uint4*)(xc + t0 + 4);
        float xr[17];
        xr[0]  = first ? bfhi(U0.x) : bfhi(xc[t0 - 1]);
        xr[1]  = bflo(U0.x); xr[2]  = bfhi(U0.x);
        xr[3]  = bflo(U0.y); xr[4]  = bfhi(U0.y);
        xr[5]  = bflo(U0.z); xr[6]  = bfhi(U0.z);
        xr[7]  = bflo(U0.w); xr[8]  = bfhi(U0.w);
        xr[9]  = bflo(U1.x); xr[10] = bfhi(U1.x);
        xr[11] = bflo(U1.y); xr[12] = bfhi(U1.y);
        xr[13] = bflo(U1.z); xr[14] = bfhi(U1.z);
        xr[15] = bflo(U1.w); xr[16] = bfhi(U1.w);

        float wv[24];
        const float* wb = &wl[cl * 48 + half * 8];
        *(float4*)(wv + 0)  = *(const float4*)(wb + 0);
        *(float4*)(wv + 4)  = *(const float4*)(wb + 4);
        *(float4*)(wv + 8)  = *(const float4*)(wb + 16);
        *(float4*)(wv + 12) = *(const float4*)(wb + 20);
        *(float4*)(wv + 16) = *(const float4*)(wb + 32);
        *(float4*)(wv + 20) = *(const float4*)(wb + 36);
#pragma unroll
        for (int oc = 0; oc < 8; ++oc) {
            float wa = wv[oc], wq = wv[8 + oc], wc = wv[16 + oc];
#pragma unroll
            for (int i = 0; i < 8; ++i)
                acc[oc][i] += wa * xr[2 * i] + wq * xr[2 * i + 1] + wc * xr[2 * i + 2];
        }
    }

    // h1 write (bf16)
    unsigned* ob = h1b + ((size_t)b * COUTC + jo * 16 + half * 8) * (TT2 / 2) + t0 / 2;
#pragma unroll
    for (int oc = 0; oc < 8; ++oc) {
        uint4 o;
        o.x = packbf(acc[oc][0], acc[oc][1]);
        o.y = packbf(acc[oc][2], acc[oc][3]);
        o.z = packbf(acc[oc][4], acc[oc][5]);
        o.w = packbf(acc[oc][6], acc[oc][7]);
        *(uint4*)(ob + (size_t)oc * (TT2 / 2)) = o;
    }

    // GN partials for sub-block sb = jo*2 + half (on fp32 acc)
    float s = 0.f, ss = 0.f;
#pragma unroll
    for (int oc = 0; oc < 8; ++oc)
#pragma unroll
        for (int i = 0; i < 8; ++i) { float v = acc[oc][i]; s += v; ss += v * v; }
    for (int o = 32; o; o >>= 1) {
        s  += __shfl_down(s, o, 64);
        ss += __shfl_down(ss, o, 64);
    }
    const int lane = tid & 63, wv2 = tid >> 6;
    if (lane == 0) { red[wv2][0] = s; red[wv2][1] = ss; }
    __syncthreads();
    if (tid == 0) {
        size_t o = (((size_t)b * 50 + jo * 2 + 0) * 4 + blockIdx.x) * 2;
        part[o] = red[0][0] + red[1][0];
        part[o + 1] = red[0][1] + red[1][1];
    }
    if (tid == 128) {
        size_t o = (((size_t)b * 50 + jo * 2 + 1) * 4 + blockIdx.x) * 2;
        part[o] = red[2][0] + red[3][0];
        part[o + 1] = red[2][1] + red[3][1];
    }
}

// ------- Kernel C: finalize stats -------------------------------------------------
__global__ void gn_final(const float* __restrict__ part, float* __restrict__ stats)
{
    int i = threadIdx.x;
    if (i < BATCH * NGROUP) {
        int b = i / NGROUP, g = i % NGROUP;
        float s = 0.f, ss = 0.f;
        for (int sb = 0; sb < 5; ++sb)
            for (int xb = 0; xb < 4; ++xb) {
                size_t o = (((size_t)b * 50 + g * 5 + sb) * 4 + xb) * 2;
                s  += part[o];
                ss += part[o + 1];
            }
        const float invN = 1.0f / (float)(CPG * TT2);
        float mean = s * invN;
        float var  = ss * invN - mean * mean;
        stats[i * 2]     = mean;
        stats[i * 2 + 1] = rsqrtf(var + 1e-5f);
    }
}

// ------- Kernel D: per-(b,ch) GN coefficients ------------------------------------
__global__ void gn_coef(const float* __restrict__ stats, const float* __restrict__ gamma,
                        const float* __restrict__ beta, float* __restrict__ AB)
{
    int idx = blockIdx.x * 256 + threadIdx.x;
    if (idx < BATCH * COUTC) {
        int b = idx / COUTC; int ch = idx - b * COUTC;
        int g = ch / CPG;
        float m = stats[(b * NGROUP + g) * 2];
        float r = stats[(b * NGROUP + g) * 2 + 1];
        float A = r * gamma[ch];
        AB[(size_t)idx * 2]     = A;
        AB[(size_t)idx * 2 + 1] = beta[ch] - m * A;
    }
}

// ------- Kernel E: streaming GN-apply + add s + pool + PReLU ---------------------
// grid (4, 28, 16), block 256, 4 t2/thread
__global__ __launch_bounds__(256) void final2pb(
    const unsigned* __restrict__ h1b, const unsigned* __restrict__ sb,
    const float* __restrict__ AB, const float* __restrict__ a1,
    float* __restrict__ outb)
{
    const int n     = blockIdx.y >> 1;
    const int chalf = blockIdx.y & 1;
    const int b     = blockIdx.z;
    const int tid   = threadIdx.x;
    const int t0    = (blockIdx.x * 256 + tid) * 4;   // t2

    int js[2];
    js[0] = PAIR_A[n];
    const int jb = PAIR_B[n];
    const int L = (jb >= 0) ? 2 : 1;
    js[1] = (jb >= 0) ? jb : js[0];

    __shared__ float Al[2][8], Bl[2][8];
    if (tid < 16) {
        int ji = tid >> 3, c8 = tid & 7;
        int ch = js[ji] * 16 + chalf * 8 + c8;
        Al[ji][c8] = AB[((size_t)b * COUTC + ch) * 2];
        Bl[ji][c8] = AB[((size_t)b * COUTC + ch) * 2 + 1];
    }
    __syncthreads();

    const float alpha = a1[0];
    const float invL  = (L == 2) ? 0.5f : 1.0f;

    float acc[8][4];
#pragma unroll
    for (int c = 0; c < 8; ++c)
#pragma unroll
        for (int i = 0; i < 4; ++i) acc[c][i] = 0.f;

    for (int ji = 0; ji < L; ++ji) {
        const int jc0 = js[ji] * 16 + chalf * 8;
#pragma unroll
        for (int c = 0; c < 8; ++c) {
            size_t rowoff = ((size_t)b * COUTC + jc0 + c) * (TT2 / 2) + t0 / 2;
            uint2 hv = *(const uint2*)(h1b + rowoff);
            uint2 sv = *(const uint2*)(sb + rowoff);
            float A = Al[ji][c], Bc = Bl[ji][c];
            acc[c][0] += bflo(hv.x) * A + Bc + bflo(sv.x);
            acc[c][1] += bfhi(hv.x) * A + Bc + bfhi(sv.x);
            acc[c][2] += bflo(hv.y) * A + Bc + bflo(sv.y);
            acc[c][3] += bfhi(hv.y) * A + Bc + bfhi(sv.y);
        }
    }

    float* ob = outb + ((size_t)b * 224 + n * 16 + chalf * 8) * TT2 + t0;
#pragma unroll
    for (int c = 0; c < 8; ++c) {
        float4 o;
#pragma unroll
        for (int i = 0; i < 4; ++i) {
            float v = acc[c][i] * invL;
            ((float*)&o)[i] = (v >= 0.f) ? v : alpha * v;
        }
        *(float4*)(ob + (size_t)c * TT2) = o;
    }
}

extern "C" void kernel_launch(void* const* d_in, const int* in_sizes, int n_in,
                              void* d_out, int out_size, void* d_ws, size_t ws_size,
                              hipStream_t stream) {
    const float* x     = (const float*)d_in[0];
    const float* w0    = (const float*)d_in[1];
    const float* b0    = (const float*)d_in[2];
    const float* a0    = (const float*)d_in[3];
    const float* w1    = (const float*)d_in[4];
    const float* b1    = (const float*)d_in[5];
    const float* gamma = (const float*)d_in[6];
    const float* beta  = (const float*)d_in[7];
    const float* wsc   = (const float*)d_in[8];
    const float* bsc   = (const float*)d_in[9];
    const float* a1    = (const float*)d_in[10];
    float* out = (float*)d_out;

    unsigned* h0b = (unsigned*)d_ws;                            // 13,107,200 uints (bf16 x2)
    unsigned* sbf = h0b + (size_t)BATCH * CIN * (T1 / 2);       // 13,107,200 uints
    unsigned* h1b = sbf + (size_t)BATCH * COUTC * (TT2 / 2);    // 13,107,200 uints
    float* part   = (float*)(h1b + (size_t)BATCH * COUTC * (TT2 / 2));  // 6,400 floats
    float* stats  = part + BATCH * 50 * 4 * 2;                  // 320 floats
    float* AB     = stats + BATCH * NGROUP * 2;                 // 12,800 floats

    conv0j<<<dim3(T1 / 2048, NJ, BATCH), 256, 0, stream>>>(x, w0, b0, a0, wsc, bsc, h0b, sbf);
    conv1_gn8b<<<dim3(TT2 / 1024, NJ, BATCH), 256, 0, stream>>>(h0b, w1, b1, h1b, part);
    gn_final<<<1, 256, 0, stream>>>(part, stats);
    gn_coef<<<dim3(25), 256, 0, stream>>>(stats, gamma, beta, AB);
    final2pb<<<dim3(TT2 / 1024, NPOOL * 2, BATCH), 256, 0, stream>>>(h1b, sbf, AB, a1, out);
}

// Round 7
// 314.445 us; speedup vs baseline: 3.2206x; 1.4162x over previous
//
#include <hip/hip_runtime.h>

#define BATCH 16
#define CIN   200
#define T1    8192
#define COUTC 400
#define TT2   4096
#define NJ    25
#define NGROUP 10
#define CPG   40
#define NPOOL 14

__constant__ int NBR_OFF[NJ + 1] = {0,8,14,18,21,29,35,39,42,50,56,63,72,80,85,94,101,106,110,113,122,129,134,138,141,145};
__constant__ int NBR[145] = {
 0,1,2,4,5,8,9,24,
 0,1,2,3,4,8,
 0,1,2,3,
 1,2,3,
 0,1,4,5,6,8,9,24,
 0,4,5,6,7,8,
 4,5,6,7,
 5,6,7,
 0,1,4,5,8,9,10,24,
 0,4,8,9,10,11,
 8,9,10,11,12,14,19,
 9,10,11,12,13,14,15,19,20,
 10,11,12,13,14,15,19,20,
 11,12,13,14,19,
 10,11,12,13,14,15,16,19,20,
 11,12,14,15,16,17,19,
 14,15,16,17,18,
 15,16,17,18,
 16,17,18,
 10,11,12,13,14,15,19,20,21,
 11,12,14,19,20,21,22,
 19,20,21,22,23,
 20,21,22,23,
 21,22,23,
 0,4,8,24};
__constant__ int PAIR_A[NPOOL] = {0,2,4,6,8,10,12,14,15,17,19,20,22,24};
__constant__ int PAIR_B[NPOOL] = {1,3,5,7,9,11,13,-1,16,18,-1,21,23,-1};
// joints sorted by degree desc (heavy blocks dispatch first -> smaller tail)
__constant__ int JORD[NJ] = {11,14,19,0,4,8,12,10,15,20,1,5,9,13,16,21,2,6,17,22,24,3,7,18,23};

// ---- bf16 helpers (RNE pack, shift unpack) ----
__device__ __forceinline__ unsigned bfround(float f) {
    unsigned u = __builtin_bit_cast(unsigned, f);
    return (u + 0x7FFFu + ((u >> 16) & 1u)) >> 16;
}
__device__ __forceinline__ unsigned packbf(float lo, float hi) {
    return bfround(lo) | (bfround(hi) << 16);
}
__device__ __forceinline__ float bflo(unsigned u) { return __builtin_bit_cast(float, u << 16); }
__device__ __forceinline__ float bfhi(unsigned u) { return __builtin_bit_cast(float, u & 0xFFFF0000u); }

// ------- Kernel A: conv0 (K=3,s=1,reflect)+PReLU + shortcut (K=1,s=2), prefetch --
// grid (8, 25, 16), block 256, 4 t/thread.  h0b bf16 (B,200,8192); sb bf16 (B,400,4096)
__global__ __launch_bounds__(256) void conv0j4(
    const float* __restrict__ x, const float* __restrict__ w0,
    const float* __restrict__ b0, const float* __restrict__ a0,
    const float* __restrict__ wsc, const float* __restrict__ bsc,
    unsigned* __restrict__ h0b, unsigned* __restrict__ sb)
{
    const int jo  = JORD[blockIdx.y];
    const int b   = blockIdx.z;
    const int tid = threadIdx.x;
    const int t0  = (blockIdx.x * 256 + tid) * 4;

    const int off = NBR_OFF[jo];
    const int n8  = (NBR_OFF[jo + 1] - off) * 8;

    __shared__ float wl[72 * 24];    // conv0 weights [cl][k][oc]
    __shared__ float wsl[72 * 16];   // shortcut weights [cl][c]
    __shared__ int   cil[72];
    __shared__ float bl[8], bsl[16];

    for (int i = tid; i < n8; i += 256)
        cil[i] = NBR[off + (i >> 3)] * 8 + (i & 7);
    for (int idx = tid; idx < n8 * 24; idx += 256) {
        int cl = idx / 24; int r = idx - cl * 24; int k = r >> 3; int oc = r & 7;
        int ci = NBR[off + (cl >> 3)] * 8 + (cl & 7);
        wl[idx] = w0[(size_t)(jo * 8 + oc) * 600 + ci * 3 + k];
    }
    for (int idx = tid; idx < n8 * 16; idx += 256) {
        int cl = idx >> 4; int c = idx & 15;
        int ci = NBR[off + (cl >> 3)] * 8 + (cl & 7);
        wsl[idx] = wsc[(size_t)(jo * 16 + c) * 200 + ci];
    }
    if (tid < 8)  bl[tid]  = b0[jo * 8 + tid];
    if (tid < 16) bsl[tid] = bsc[jo * 16 + tid];
    __syncthreads();

    const float alpha = a0[0];
    const bool first = (t0 == 0);
    const bool last  = (t0 + 4 == T1);
    const int idx_m = first ? 1 : t0 - 1;          // clamped, reflect-correct
    const int idx_p = last ? (T1 - 2) : t0 + 4;
    const float* xb = x + (size_t)b * CIN * T1;

    float acc[8][4];
#pragma unroll
    for (int oc = 0; oc < 8; ++oc) {
        float bv = bl[oc];
#pragma unroll
        for (int i = 0; i < 4; ++i) acc[oc][i] = bv;
    }
    float sacc[16][2];
#pragma unroll
    for (int c = 0; c < 16; ++c) { sacc[c][0] = bsl[c]; sacc[c][1] = bsl[c]; }

    // prefetch cl=0
    const float* xc0 = xb + (size_t)cil[0] * T1;
    float4 v  = *(const float4*)(xc0 + t0);
    float  xm = xc0[idx_m];
    float  xp = xc0[idx_p];

    for (int cl = 0; cl < n8; ++cl) {
        float4 vc = v; float xmc = xm, xpc = xp;
        if (cl + 1 < n8) {                          // prefetch next cl
            const float* xn = xb + (size_t)cil[cl + 1] * T1;
            v  = *(const float4*)(xn + t0);
            xm = xn[idx_m];
            xp = xn[idx_p];
        }
        float xs[6] = {xmc, vc.x, vc.y, vc.z, vc.w, xpc};
        const float* wrow = &wl[cl * 24];
#pragma unroll
        for (int k = 0; k < 3; ++k) {
            float wv[8];
            *(float4*)(wv)     = *(const float4*)(wrow + k * 8);
            *(float4*)(wv + 4) = *(const float4*)(wrow + k * 8 + 4);
#pragma unroll
            for (int oc = 0; oc < 8; ++oc)
#pragma unroll
                for (int i = 0; i < 4; ++i)
                    acc[oc][i] += wv[oc] * xs[i + k];
        }
        const float* wsr = &wsl[cl * 16];
#pragma unroll
        for (int q = 0; q < 4; ++q) {
            float wsv[4];
            *(float4*)(wsv) = *(const float4*)(wsr + 4 * q);
#pragma unroll
            for (int c = 0; c < 4; ++c) {
                sacc[4 * q + c][0] += wsv[c] * vc.x;
                sacc[4 * q + c][1] += wsv[c] * vc.z;
            }
        }
    }

    // h0 write: prelu + bf16 pack (4 t = uint2 per row)
    unsigned* hb = h0b + ((size_t)b * CIN + jo * 8) * (T1 / 2) + t0 / 2;
#pragma unroll
    for (int oc = 0; oc < 8; ++oc) {
        float v0 = acc[oc][0] >= 0.f ? acc[oc][0] : alpha * acc[oc][0];
        float v1 = acc[oc][1] >= 0.f ? acc[oc][1] : alpha * acc[oc][1];
        float v2 = acc[oc][2] >= 0.f ? acc[oc][2] : alpha * acc[oc][2];
        float v3 = acc[oc][3] >= 0.f ? acc[oc][3] : alpha * acc[oc][3];
        uint2 o; o.x = packbf(v0, v1); o.y = packbf(v2, v3);
        *(uint2*)(hb + (size_t)oc * (T1 / 2)) = o;
    }

    // shortcut write (unpooled, 2 t2 = 1 uint per row)
    unsigned* sbp = sb + ((size_t)b * COUTC + jo * 16) * (TT2 / 2) + t0 / 4;
#pragma unroll
    for (int c = 0; c < 16; ++c)
        sbp[(size_t)c * (TT2 / 2)] = packbf(sacc[c][0], sacc[c][1]);
}

// ------- Kernel B: conv1 (K=3,s=2,reflect) + GN partials, bf16, prefetch ---------
// grid (4, 25, 16), block 256.  h1b bf16 (B,400,4096); part[b][50][4][2]
__global__ __launch_bounds__(256) void conv1_gn8p(
    const unsigned* __restrict__ h0b, const float* __restrict__ w1,
    const float* __restrict__ b1, unsigned* __restrict__ h1b,
    float* __restrict__ part)
{
    const int jo   = JORD[blockIdx.y];
    const int b    = blockIdx.z;
    const int tid  = threadIdx.x;
    const int half = tid >> 7;
    const int tl   = tid & 127;
    const int t0   = blockIdx.x * 1024 + tl * 8;   // t2 units == uint index

    const int off = NBR_OFF[jo];
    const int n8  = (NBR_OFF[jo + 1] - off) * 8;

    __shared__ float wl[72 * 48];   // [cl][k][16oc]
    __shared__ int   cil[72];
    __shared__ float red[4][2];

    for (int i = tid; i < n8; i += 256)
        cil[i] = NBR[off + (i >> 3)] * 8 + (i & 7);
    for (int idx = tid; idx < n8 * 48; idx += 256) {
        int cl = idx / 48; int r = idx - cl * 48; int k = r >> 4; int oc = r & 15;
        int ci = NBR[off + (cl >> 3)] * 8 + (cl & 7);
        wl[idx] = w1[(size_t)(jo * 16 + oc) * 600 + ci * 3 + k];
    }
    __syncthreads();

    float acc[8][8];
#pragma unroll
    for (int oc = 0; oc < 8; ++oc) {
        float bv = b1[jo * 16 + half * 8 + oc];
#pragma unroll
        for (int i = 0; i < 8; ++i) acc[oc][i] = bv;
    }

    const bool first = (t0 == 0);
    const int idx_m = first ? 0 : t0 - 1;          // clamped: bfhi(uint0)=x[1]
    const unsigned* hb = h0b + (size_t)b * CIN * (T1 / 2);

    // prefetch cl=0
    const unsigned* xc0 = hb + (size_t)cil[0] * (T1 / 2);
    uint4 U0 = *(const uint4*)(xc0 + t0);
    uint4 U1 = *(const uint4*)(xc0 + t0 + 4);
    unsigned up = xc0[idx_m];

    for (int cl = 0; cl < n8; ++cl) {
        uint4 A0 = U0, A1 = U1; unsigned upc = up;
        if (cl + 1 < n8) {                          // prefetch next cl
            const unsigned* xn = hb + (size_t)cil[cl + 1] * (T1 / 2);
            U0 = *(const uint4*)(xn + t0);
            U1 = *(const uint4*)(xn + t0 + 4);
            up = xn[idx_m];
        }
        float xr[17];
        xr[0]  = bfhi(upc);
        xr[1]  = bflo(A0.x); xr[2]  = bfhi(A0.x);
        xr[3]  = bflo(A0.y); xr[4]  = bfhi(A0.y);
        xr[5]  = bflo(A0.z); xr[6]  = bfhi(A0.z);
        xr[7]  = bflo(A0.w); xr[8]  = bfhi(A0.w);
        xr[9]  = bflo(A1.x); xr[10] = bfhi(A1.x);
        xr[11] = bflo(A1.y); xr[12] = bfhi(A1.y);
        xr[13] = bflo(A1.z); xr[14] = bfhi(A1.z);
        xr[15] = bflo(A1.w); xr[16] = bfhi(A1.w);

        const float* wb = &wl[cl * 48 + half * 8];
#pragma unroll
        for (int k = 0; k < 3; ++k) {
            float wv[8];
            *(float4*)(wv)     = *(const float4*)(wb + k * 16);
            *(float4*)(wv + 4) = *(const float4*)(wb + k * 16 + 4);
#pragma unroll
            for (int oc = 0; oc < 8; ++oc)
#pragma unroll
                for (int i = 0; i < 8; ++i)
                    acc[oc][i] += wv[oc] * xr[2 * i + k];
        }
    }

    // h1 write (bf16)
    unsigned* ob = h1b + ((size_t)b * COUTC + jo * 16 + half * 8) * (TT2 / 2) + t0 / 2;
#pragma unroll
    for (int oc = 0; oc < 8; ++oc) {
        uint4 o;
        o.x = packbf(acc[oc][0], acc[oc][1]);
        o.y = packbf(acc[oc][2], acc[oc][3]);
        o.z = packbf(acc[oc][4], acc[oc][5]);
        o.w = packbf(acc[oc][6], acc[oc][7]);
        *(uint4*)(ob + (size_t)oc * (TT2 / 2)) = o;
    }

    // GN partials for sub-block sb = jo*2 + half (fp32 acc)
    float s = 0.f, ss = 0.f;
#pragma unroll
    for (int oc = 0; oc < 8; ++oc)
#pragma unroll
        for (int i = 0; i < 8; ++i) { float v = acc[oc][i]; s += v; ss += v * v; }
    for (int o = 32; o; o >>= 1) {
        s  += __shfl_down(s, o, 64);
        ss += __shfl_down(ss, o, 64);
    }
    const int lane = tid & 63, wv2 = tid >> 6;
    if (lane == 0) { red[wv2][0] = s; red[wv2][1] = ss; }
    __syncthreads();
    if (tid == 0) {
        size_t o = (((size_t)b * 50 + jo * 2 + 0) * 4 + blockIdx.x) * 2;
        part[o] = red[0][0] + red[1][0];
        part[o + 1] = red[0][1] + red[1][1];
    }
    if (tid == 128) {
        size_t o = (((size_t)b * 50 + jo * 2 + 1) * 4 + blockIdx.x) * 2;
        part[o] = red[2][0] + red[3][0];
        part[o + 1] = red[2][1] + red[3][1];
    }
}

// ------- Kernel C: finalize stats -------------------------------------------------
__global__ void gn_final(const float* __restrict__ part, float* __restrict__ stats)
{
    int i = threadIdx.x;
    if (i < BATCH * NGROUP) {
        int b = i / NGROUP, g = i % NGROUP;
        float s = 0.f, ss = 0.f;
        for (int sb = 0; sb < 5; ++sb)
            for (int xb = 0; xb < 4; ++xb) {
                size_t o = (((size_t)b * 50 + g * 5 + sb) * 4 + xb) * 2;
                s  += part[o];
                ss += part[o + 1];
            }
        const float invN = 1.0f / (float)(CPG * TT2);
        float mean = s * invN;
        float var  = ss * invN - mean * mean;
        stats[i * 2]     = mean;
        stats[i * 2 + 1] = rsqrtf(var + 1e-5f);
    }
}

// ------- Kernel D: per-(b,ch) GN coefficients ------------------------------------
__global__ void gn_coef(const float* __restrict__ stats, const float* __restrict__ gamma,
                        const float* __restrict__ beta, float* __restrict__ AB)
{
    int idx = blockIdx.x * 256 + threadIdx.x;
    if (idx < BATCH * COUTC) {
        int b = idx / COUTC; int ch = idx - b * COUTC;
        int g = ch / CPG;
        float m = stats[(b * NGROUP + g) * 2];
        float r = stats[(b * NGROUP + g) * 2 + 1];
        float A = r * gamma[ch];
        AB[(size_t)idx * 2]     = A;
        AB[(size_t)idx * 2 + 1] = beta[ch] - m * A;
    }
}

// ------- Kernel E: streaming GN-apply + add s + pool + PReLU ---------------------
// grid (4, 28, 16), block 256, 4 t2/thread
__global__ __launch_bounds__(256) void final2pb(
    const unsigned* __restrict__ h1b, const unsigned* __restrict__ sb,
    const float* __restrict__ AB, const float* __restrict__ a1,
    float* __restrict__ outb)
{
    const int n     = blockIdx.y >> 1;
    const int chalf = blockIdx.y & 1;
    const int b     = blockIdx.z;
    const int tid   = threadIdx.x;
    const int t0    = (blockIdx.x * 256 + tid) * 4;   // t2

    int js[2];
    js[0] = PAIR_A[n];
    const int jb = PAIR_B[n];
    const int L = (jb >= 0) ? 2 : 1;
    js[1] = (jb >= 0) ? jb : js[0];

    __shared__ float Al[2][8], Bl[2][8];
    if (tid < 16) {
        int ji = tid >> 3, c8 = tid & 7;
        int ch = js[ji] * 16 + chalf * 8 + c8;
        Al[ji][c8] = AB[((size_t)b * COUTC + ch) * 2];
        Bl[ji][c8] = AB[((size_t)b * COUTC + ch) * 2 + 1];
    }
    __syncthreads();

    const float alpha = a1[0];
    const float invL  = (L == 2) ? 0.5f : 1.0f;

    float acc[8][4];
#pragma unroll
    for (int c = 0; c < 8; ++c)
#pragma unroll
        for (int i = 0; i < 4; ++i) acc[c][i] = 0.f;

    for (int ji = 0; ji < L; ++ji) {
        const int jc0 = js[ji] * 16 + chalf * 8;
#pragma unroll
        for (int c = 0; c < 8; ++c) {
            size_t rowoff = ((size_t)b * COUTC + jc0 + c) * (TT2 / 2) + t0 / 2;
            uint2 hv = *(const uint2*)(h1b + rowoff);
            uint2 sv = *(const uint2*)(sb + rowoff);
            float A = Al[ji][c], Bc = Bl[ji][c];
            acc[c][0] += bflo(hv.x) * A + Bc + bflo(sv.x);
            acc[c][1] += bfhi(hv.x) * A + Bc + bfhi(sv.x);
            acc[c][2] += bflo(hv.y) * A + Bc + bflo(sv.y);
            acc[c][3] += bfhi(hv.y) * A + Bc + bfhi(sv.y);
        }
    }

    float* ob = outb + ((size_t)b * 224 + n * 16 + chalf * 8) * TT2 + t0;
#pragma unroll
    for (int c = 0; c < 8; ++c) {
        float4 o;
#pragma unroll
        for (int i = 0; i < 4; ++i) {
            float v = acc[c][i] * invL;
            ((float*)&o)[i] = (v >= 0.f) ? v : alpha * v;
        }
        *(float4*)(ob + (size_t)c * TT2) = o;
    }
}

extern "C" void kernel_launch(void* const* d_in, const int* in_sizes, int n_in,
                              void* d_out, int out_size, void* d_ws, size_t ws_size,
                              hipStream_t stream) {
    const float* x     = (const float*)d_in[0];
    const float* w0    = (const float*)d_in[1];
    const float* b0    = (const float*)d_in[2];
    const float* a0    = (const float*)d_in[3];
    const float* w1    = (const float*)d_in[4];
    const float* b1    = (const float*)d_in[5];
    const float* gamma = (const float*)d_in[6];
    const float* beta  = (const float*)d_in[7];
    const float* wsc   = (const float*)d_in[8];
    const float* bsc   = (const float*)d_in[9];
    const float* a1    = (const float*)d_in[10];
    float* out = (float*)d_out;

    unsigned* h0b = (unsigned*)d_ws;                            // bf16 pairs
    unsigned* sbf = h0b + (size_t)BATCH * CIN * (T1 / 2);
    unsigned* h1b = sbf + (size_t)BATCH * COUTC * (TT2 / 2);
    float* part   = (float*)(h1b + (size_t)BATCH * COUTC * (TT2 / 2));
    float* stats  = part + BATCH * 50 * 4 * 2;
    float* AB     = stats + BATCH * NGROUP * 2;

    conv0j4<<<dim3(T1 / 1024, NJ, BATCH), 256, 0, stream>>>(x, w0, b0, a0, wsc, bsc, h0b, sbf);
    conv1_gn8p<<<dim3(TT2 / 1024, NJ, BATCH), 256, 0, stream>>>(h0b, w1, b1, h1b, part);
    gn_final<<<1, 256, 0, stream>>>(part, stats);
    gn_coef<<<dim3(25), 256, 0, stream>>>(stats, gamma, beta, AB);
    final2pb<<<dim3(TT2 / 1024, NPOOL * 2, BATCH), 256, 0, stream>>>(h1b, sbf, AB, a1, out);
}